// Round 7
// baseline (786.173 us; speedup 1.0000x reference)
//
#include <hip/hip_runtime.h>
#include <math.h>

#define Bv   64
#define Nv   900
#define Mv   64
#define NCls 128
#define NCOLS (Nv + 1)          // 901 columns incl. dummy col 0
#define KREG 15                 // columns per lane: j = t + 64k, k=0..14
#define INFV 1000000000.0f

// uniform dynamic read of a constant-indexed register array (stays in VGPRs)
#define SEL15(arr, kidx, dst) do {            \
    int _s = arr[0];                          \
    _Pragma("unroll")                         \
    for (int _kk = 1; _kk < KREG; _kk++)      \
        _s = ((kidx) == _kk) ? arr[_kk] : _s; \
    (dst) = _s;                               \
} while (0)

// uniform dynamic write (lane-targeted, register-indexed by uniform kidx)
#define SET15(arr, kidx, val) do {            \
    _Pragma("unroll")                         \
    for (int _kk = 0; _kk < KREG; _kk++)      \
        if ((kidx) == _kk) arr[_kk] = (val);  \
} while (0)

// ---------------------------------------------------------------------------
// Kernel 1: cost C[b][n][m] — certified (R3/R5).
// ---------------------------------------------------------------------------
__global__ __launch_bounds__(64) void cost_kernel(
    const float* __restrict__ logits,   // [B,N,128]
    const float* __restrict__ corners,  // [B,N,8,3]
    const int*   __restrict__ labels,   // [B,64]
    const float* __restrict__ boxes,    // [B,64,7]
    float*       __restrict__ C)        // [B,N,64]
{
    const int n = blockIdx.x, b = blockIdx.y, t = threadIdx.x;
    const long bn = (long)b * Nv + n;

    const float2 l2 = ((const float2*)(logits + bn * NCls))[t];
    float e0 = expf(l2.x), e1 = expf(l2.y);

    __shared__ float probs[NCls];
    ((float2*)probs)[t] = make_float2(e0, e1);

    float s = e0 + e1;
    #pragma unroll
    for (int off = 1; off < 64; off <<= 1) s += __shfl_xor(s, off, 64);

    const float* cp = corners + bn * 24;
    float cx = 0.f, cy = 0.f, cz = 0.f;
    if (t < 8) { cx = cp[3 * t]; cy = cp[3 * t + 1]; cz = cp[3 * t + 2]; }
    #pragma unroll
    for (int off = 1; off < 8; off <<= 1) {
        cx += __shfl_xor(cx, off, 64);
        cy += __shfl_xor(cy, off, 64);
        cz += __shfl_xor(cz, off, 64);
    }
    cx = __shfl(cx, 0, 64) * 0.125f;
    cy = __shfl(cy, 0, 64) * 0.125f;
    cz = __shfl(cz, 0, 64) * 0.125f;

    __syncthreads();

    int lbl = labels[b * Mv + t];
    float pm = probs[lbl] / s;
    const float* bx = boxes + ((long)b * Mv + t) * 7;
    float dx = cx - bx[0], dy = cy - bx[1], dz = cz - bx[2];
    float d = sqrtf(dx * dx + dy * dy + dz * dz);

    C[bn * Mv + t] = 5.0f * d - pm;
}

// ---------------------------------------------------------------------------
// Kernel 2: LSA = certified R5 skeleton (u=rowmin, v=0) + LAPJV augmenting
// row reduction (ARR) before SSP. ARR lowers v only on MATCHED columns
// (free columns keep v=0 — required for rectangular-LSA correctness; the
// colmin init of R4/R6 violated exactly this and is dead).
// ---------------------------------------------------------------------------
__global__ __launch_bounds__(64) void lsa_kernel(
    const float* __restrict__ C,      // [B,N,M]
    float* __restrict__ outPred, float* __restrict__ outTgt)
{
    const int b = blockIdx.x;
    const int t = threadIdx.x;
    const float* cb = C + (size_t)b * Nv * Mv;

    // ---- Phase A: row argmin (lane t = row t+1); 4 disjoint ranges for ILP
    float mv0 = INFV, mv1 = INFV, mv2 = INFV, mv3 = INFV;
    int   mj0 = 0,    mj1 = 0,    mj2 = 0,    mj3 = 0;
    #pragma unroll 5
    for (int n = 0; n < 225; ++n) {
        float c0 = cb[(size_t)(n      ) * Mv + t];
        float c1 = cb[(size_t)(n + 225) * Mv + t];
        float c2 = cb[(size_t)(n + 450) * Mv + t];
        float c3 = cb[(size_t)(n + 675) * Mv + t];
        if (c0 < mv0) { mv0 = c0; mj0 = n;       }
        if (c1 < mv1) { mv1 = c1; mj1 = n + 225; }
        if (c2 < mv2) { mv2 = c2; mj2 = n + 450; }
        if (c3 < mv3) { mv3 = c3; mj3 = n + 675; }
    }
    float rowmin = mv0; int rown = mj0;
    if (mv1 < rowmin) { rowmin = mv1; rown = mj1; }
    if (mv2 < rowmin) { rowmin = mv2; rown = mj2; }
    if (mv3 < rowmin) { rowmin = mv3; rown = mj3; }

    float u_reg = rowmin;            // lane l holds u[l+1]
    const int jcol = rown + 1;       // chosen column 1..900

    // ---- Phase B: duplicate detection (first occurrence wins)
    bool isdup = false;
    #pragma unroll
    for (int s = 1; s < 64; ++s) {
        int oj = __shfl(jcol, (t + 64 - s) & 63, 64);
        isdup |= (oj == jcol) && (s <= t);
    }
    unsigned long long pending = __ballot(isdup);

    int   p_reg[KREG], way_reg[KREG];
    float v_reg[KREG], minv[KREG];
    #pragma unroll
    for (int k = 0; k < KREG; k++) { p_reg[k] = 0; way_reg[k] = 0; v_reg[k] = 0.f; }

    int rowcol = isdup ? 0 : jcol;   // lane i: column assigned to row i+1

    // scatter winners into distributed p[]
    #pragma unroll 8
    for (int i = 0; i < 64; ++i) {
        int jb = __shfl(jcol, i, 64);
        if (!((pending >> i) & 1ull) && t == (jb & 63))
            SET15(p_reg, jb >> 6, i + 1);
    }

    // ---- Phase B2: LAPJV augmenting row reduction (free columns keep v=0)
    {
        unsigned long long pend = pending;
        int steps = 0;
        while (pend != 0ull && steps < 256) {
            ++steps;
            const int k = __ffsll(pend);     // 1-based unassigned row
            pend &= pend - 1;

            // scan row k: w_j = fl(C[j,k] - v_j); track (min1,j1,min2,j2)
            float w1 = INFV, w2 = INFV; int j1 = 0, j2 = 0;
            #pragma unroll
            for (int kk = 0; kk < KREG; kk++) {
                int j = t + (kk << 6);
                if (j >= 1 && j < NCOLS) {
                    float w = cb[(size_t)(j - 1) * Mv + (k - 1)] - v_reg[kk];
                    if (w < w1)      { w2 = w1; j2 = j1; w1 = w; j1 = j; }
                    else if (w < w2) { w2 = w;  j2 = j; }
                }
            }
            #pragma unroll
            for (int off = 1; off < 64; off <<= 1) {
                float ow1 = __shfl_xor(w1, off, 64);
                int   oj1 = __shfl_xor(j1, off, 64);
                float ow2 = __shfl_xor(w2, off, 64);
                int   oj2 = __shfl_xor(j2, off, 64);
                if (ow1 < w1 || (ow1 == w1 && oj1 < j1)) {
                    if (w1 < ow2 || (w1 == ow2 && j1 < oj2)) { w2 = w1;  j2 = j1;  }
                    else                                      { w2 = ow2; j2 = oj2; }
                    w1 = ow1; j1 = oj1;
                } else {
                    if (ow1 < w2 || (ow1 == w2 && oj1 < j2)) { w2 = ow1; j2 = oj1; }
                }
            }

            int ptmp; SEL15(p_reg, j1 >> 6, ptmp);
            const int owner1 = __shfl(ptmp, j1 & 63, 64);

            int target = j1;
            if (w1 < w2) {
                const float dlt = w2 - w1;          // lower price of j1 (it becomes matched)
                if (t == (j1 & 63)) {
                    #pragma unroll
                    for (int kk = 0; kk < KREG; kk++)
                        if ((j1 >> 6) == kk) v_reg[kk] -= dlt;
                }
            } else if (owner1 != 0) {
                target = j2;                        // tie: prefer the alternative column
            }
            if (t == k - 1) u_reg = w2;             // u_k = u2 (edge to target is tight)

            int ownerT = owner1;
            if (target != j1) {
                SEL15(p_reg, target >> 6, ptmp);
                ownerT = __shfl(ptmp, target & 63, 64);
            }
            if (t == (target & 63)) SET15(p_reg, target >> 6, k);
            if (t == k - 1) rowcol = target;
            if (ownerT != 0) {
                if (t == ownerT - 1) rowcol = 0;    // displaced row
                pend |= 1ull << (ownerT - 1);
            }
        }
        pending = pend;                             // leftovers -> SSP
    }

    // ---- Phase C: SSP Dijkstra for remaining unassigned rows (certified)
    while (pending) {
        const int i1v = __ffsll(pending);    // row index (1-based)
        pending &= pending - 1;

        unsigned int usedMask = 0;
        unsigned long long rowMask = 0;
        #pragma unroll
        for (int k = 0; k < KREG; k++) minv[k] = INFV;

        int j0 = 0;
        int i0 = i1v;
        while (true) {
            if ((j0 & 63) == t) usedMask |= 1u << (j0 >> 6);
            rowMask |= 1ull << (i0 - 1);
            const float u_i0 = __shfl(u_reg, i0 - 1, 64);

            float bestv = INFV;
            int   bestj = NCOLS;
            #pragma unroll
            for (int k = 0; k < KREG; k++) {
                int j = t + (k << 6);
                if (j < NCOLS) {
                    float c   = (j == 0) ? 0.0f : cb[(size_t)(j - 1) * Mv + (i0 - 1)];
                    float cur = (c - u_i0) - v_reg[k];
                    bool used = (usedMask >> k) & 1u;
                    if (!used && cur < minv[k]) { minv[k] = cur; way_reg[k] = j0; }
                    float mval = used ? INFV : minv[k];
                    if (mval < bestv) { bestv = mval; bestj = j; }
                }
            }
            #pragma unroll
            for (int off = 1; off < 64; off <<= 1) {
                float ov = __shfl_xor(bestv, off, 64);
                int   oj = __shfl_xor(bestj, off, 64);
                if (ov < bestv || (ov == bestv && oj < bestj)) { bestv = ov; bestj = oj; }
            }
            const float delta = bestv;

            if ((rowMask >> t) & 1ull) u_reg += delta;
            #pragma unroll
            for (int k = 0; k < KREG; k++) {
                if ((usedMask >> k) & 1u) v_reg[k] -= delta;
                else                      minv[k] -= delta;
            }

            j0 = bestj;
            const int k0 = j0 >> 6, l0 = j0 & 63;
            int ptmp; SEL15(p_reg, k0, ptmp);
            i0 = __shfl(ptmp, l0, 64);
            if (i0 == 0) break;              // free column reached
        }

        // backtrack: reassign columns along augmenting path
        while (j0 != 0) {
            const int k0 = j0 >> 6, l0 = j0 & 63;
            int wtmp; SEL15(way_reg, k0, wtmp);
            const int jprev = __shfl(wtmp, l0, 64);
            int pv;
            if (jprev == 0) {
                pv = i1v;
            } else {
                int ptmp; SEL15(p_reg, jprev >> 6, ptmp);
                pv = __shfl(ptmp, jprev & 63, 64);
            }
            if (t == l0) SET15(p_reg, k0, pv);
            if (t == pv - 1) rowcol = j0;    // row->column mirror
            j0 = jprev;
        }
    }

    outPred[b * Mv + t] = (float)(rowcol - 1);
    outTgt[b * Mv + t]  = (float)t;
}

// ---------------------------------------------------------------------------
extern "C" void kernel_launch(void* const* d_in, const int* in_sizes, int n_in,
                              void* d_out, int out_size, void* d_ws, size_t ws_size,
                              hipStream_t stream)
{
    (void)in_sizes; (void)n_in; (void)out_size; (void)d_ws; (void)ws_size;

    const float* logits  = (const float*)d_in[0];   // [64,900,128] f32
    const float* corners = (const float*)d_in[1];   // [64,900,8,3] f32
    const int*   labels  = (const int*)  d_in[2];   // [64,64] i32
    const float* boxes   = (const float*)d_in[3];   // [64,64,7] f32

    float* out  = (float*)d_out;
    float* Cc   = out;                               // [64,900,64]
    float* pred = out + (size_t)Bv * Nv * Mv;        // [64,64] as f32
    float* tgt  = pred + (size_t)Bv * Mv;            // [64,64] as f32

    cost_kernel<<<dim3(Nv, Bv), 64, 0, stream>>>(logits, corners, labels, boxes, Cc);
    lsa_kernel<<<Bv, 64, 0, stream>>>(Cc, pred, tgt);
}

// Round 8
// 494.830 us; speedup vs baseline: 1.5888x; 1.5888x over previous
//
#include <hip/hip_runtime.h>
#include <math.h>

#define Bv   64
#define Nv   900
#define Mv   64
#define NCls 128
#define NCOLS (Nv + 1)          // 901 columns incl. dummy col 0
#define KREG 15                 // columns per lane: j = t + 64k, k=0..14
#define INFV 1000000000.0f

// uniform dynamic read of a constant-indexed register array (stays in VGPRs)
#define SEL15(arr, kidx, dst) do {            \
    int _s = arr[0];                          \
    _Pragma("unroll")                         \
    for (int _kk = 1; _kk < KREG; _kk++)      \
        _s = ((kidx) == _kk) ? arr[_kk] : _s; \
    (dst) = _s;                               \
} while (0)

// uniform dynamic write (lane-targeted, register-indexed by uniform kidx)
#define SET15(arr, kidx, val) do {            \
    _Pragma("unroll")                         \
    for (int _kk = 0; _kk < KREG; _kk++)      \
        if ((kidx) == _kk) arr[_kk] = (val);  \
} while (0)

// ---------------------------------------------------------------------------
// Kernel 1: cost C[b][n][m] — certified (R3/R5/R7).
// ---------------------------------------------------------------------------
__global__ __launch_bounds__(64) void cost_kernel(
    const float* __restrict__ logits,   // [B,N,128]
    const float* __restrict__ corners,  // [B,N,8,3]
    const int*   __restrict__ labels,   // [B,64]
    const float* __restrict__ boxes,    // [B,64,7]
    float*       __restrict__ C)        // [B,N,64]
{
    const int n = blockIdx.x, b = blockIdx.y, t = threadIdx.x;
    const long bn = (long)b * Nv + n;

    const float2 l2 = ((const float2*)(logits + bn * NCls))[t];
    float e0 = expf(l2.x), e1 = expf(l2.y);

    __shared__ float probs[NCls];
    ((float2*)probs)[t] = make_float2(e0, e1);

    float s = e0 + e1;
    #pragma unroll
    for (int off = 1; off < 64; off <<= 1) s += __shfl_xor(s, off, 64);

    const float* cp = corners + bn * 24;
    float cx = 0.f, cy = 0.f, cz = 0.f;
    if (t < 8) { cx = cp[3 * t]; cy = cp[3 * t + 1]; cz = cp[3 * t + 2]; }
    #pragma unroll
    for (int off = 1; off < 8; off <<= 1) {
        cx += __shfl_xor(cx, off, 64);
        cy += __shfl_xor(cy, off, 64);
        cz += __shfl_xor(cz, off, 64);
    }
    cx = __shfl(cx, 0, 64) * 0.125f;
    cy = __shfl(cy, 0, 64) * 0.125f;
    cz = __shfl(cz, 0, 64) * 0.125f;

    __syncthreads();

    int lbl = labels[b * Mv + t];
    float pm = probs[lbl] / s;
    const float* bx = boxes + ((long)b * Mv + t) * 7;
    float dx = cx - bx[0], dy = cy - bx[1], dz = cz - bx[2];
    float d = sqrtf(dx * dx + dy * dy + dz * dz);

    C[bn * Mv + t] = 5.0f * d - pm;
}

// ---------------------------------------------------------------------------
// Kernel 2: LSA — certified R5 solver (v=0, u=rowmin, dup-detect, SSP).
// NEW: Phase A fuses the row-min scan with an in-block LDS transpose writing
// CT[b][m][n] into ws. CT is written by THIS block -> lands in the local XCD
// L2 -> Phase C reads it coalesced AND warm (fixes R5's cold-CT regression).
// Solver arithmetic/logic untouched from the certified version.
// ---------------------------------------------------------------------------
__global__ __launch_bounds__(64) void lsa_kernel(
    const float* __restrict__ C,      // [B,N,M]
    float* __restrict__ CT,           // [B,M,N] scratch, or nullptr
    float* __restrict__ outPred, float* __restrict__ outTgt)
{
    const int b = blockIdx.x;
    const int t = threadIdx.x;
    const float* cb = C + (size_t)b * Nv * Mv;
    float* ctb = CT ? CT + (size_t)b * Mv * Nv : nullptr;

    __shared__ float tile[64][65];

    // ---- Phase A: row argmin (lane t = row t+1) fused with LDS transpose
    float bmv[4] = {INFV, INFV, INFV, INFV};
    int   bmj[4] = {0, 0, 0, 0};

    if (ctb) {
        for (int tl = 0; tl < 15; ++tl) {
            const int n0 = tl * 64;
            const int width = (tl == 14) ? (Nv - 14 * 64) : 64;   // 4 on last
            #pragma unroll 8
            for (int i = 0; i < width; ++i) {
                float val = cb[(size_t)(n0 + i) * Mv + t];
                tile[i][t] = val;
                int s = i & 3;                       // 4 streams for VALU ILP
                if (val < bmv[s]) { bmv[s] = val; bmj[s] = n0 + i; }
            }
            __syncthreads();
            if (t < width) {
                #pragma unroll 8
                for (int m = 0; m < 64; ++m)
                    ctb[(size_t)m * Nv + n0 + t] = tile[t][m];
            }
            __syncthreads();
        }
    } else {
        #pragma unroll 4
        for (int n = 0; n < Nv; ++n) {
            float val = cb[(size_t)n * Mv + t];
            int s = n & 3;
            if (val < bmv[s]) { bmv[s] = val; bmj[s] = n; }
        }
    }
    // merge streams (per-stream strict < keeps earliest n; index tie-break here)
    float rowmin = bmv[0]; int rown = bmj[0];
    #pragma unroll
    for (int s = 1; s < 4; ++s)
        if (bmv[s] < rowmin || (bmv[s] == rowmin && bmj[s] < rown)) {
            rowmin = bmv[s]; rown = bmj[s];
        }

    float u_reg = rowmin;            // lane l holds u[l+1]
    const int jcol = rown + 1;       // chosen column 1..900

    // ---- Phase B: duplicate detection (first occurrence wins)
    bool isdup = false;
    #pragma unroll
    for (int s = 1; s < 64; ++s) {
        int oj = __shfl(jcol, (t + 64 - s) & 63, 64);
        isdup |= (oj == jcol) && (s <= t);
    }
    unsigned long long pending = __ballot(isdup);

    int   p_reg[KREG], way_reg[KREG];
    float v_reg[KREG], minv[KREG];
    #pragma unroll
    for (int k = 0; k < KREG; k++) { p_reg[k] = 0; way_reg[k] = 0; v_reg[k] = 0.f; }

    int rowcol = isdup ? 0 : jcol;   // lane i: column assigned to row i+1

    // scatter winners into distributed p[]
    #pragma unroll 8
    for (int i = 0; i < 64; ++i) {
        int jb = __shfl(jcol, i, 64);
        if (!((pending >> i) & 1ull) && t == (jb & 63))
            SET15(p_reg, jb >> 6, i + 1);
    }

    // Phase C source: coalesced CT rows if available, else strided C
    const float* mb = ctb ? ctb : cb;
    const long   rs = ctb ? (long)Nv : 1L;
    const long   cs = ctb ? 1L : (long)Mv;

    // ---- Phase C: SSP Dijkstra for conflicted rows (certified logic)
    while (pending) {
        const int i1v = __ffsll(pending);    // row index (1-based)
        pending &= pending - 1;

        unsigned int usedMask = 0;
        unsigned long long rowMask = 0;
        #pragma unroll
        for (int k = 0; k < KREG; k++) minv[k] = INFV;

        int j0 = 0;
        int i0 = i1v;
        while (true) {
            if ((j0 & 63) == t) usedMask |= 1u << (j0 >> 6);
            rowMask |= 1ull << (i0 - 1);
            const float u_i0 = __shfl(u_reg, i0 - 1, 64);
            const float* rb = mb + (size_t)(i0 - 1) * rs;

            float bestv = INFV;
            int   bestj = NCOLS;
            #pragma unroll
            for (int k = 0; k < KREG; k++) {
                int j = t + (k << 6);
                if (j < NCOLS) {
                    float c   = (j == 0) ? 0.0f : rb[(size_t)(j - 1) * cs];
                    float cur = (c - u_i0) - v_reg[k];
                    bool used = (usedMask >> k) & 1u;
                    if (!used && cur < minv[k]) { minv[k] = cur; way_reg[k] = j0; }
                    float mval = used ? INFV : minv[k];
                    if (mval < bestv) { bestv = mval; bestj = j; }
                }
            }
            #pragma unroll
            for (int off = 1; off < 64; off <<= 1) {
                float ov = __shfl_xor(bestv, off, 64);
                int   oj = __shfl_xor(bestj, off, 64);
                if (ov < bestv || (ov == bestv && oj < bestj)) { bestv = ov; bestj = oj; }
            }
            const float delta = bestv;

            if ((rowMask >> t) & 1ull) u_reg += delta;
            #pragma unroll
            for (int k = 0; k < KREG; k++) {
                if ((usedMask >> k) & 1u) v_reg[k] -= delta;
                else                      minv[k] -= delta;
            }

            j0 = bestj;
            const int k0 = j0 >> 6, l0 = j0 & 63;
            int ptmp; SEL15(p_reg, k0, ptmp);
            i0 = __shfl(ptmp, l0, 64);
            if (i0 == 0) break;              // free column reached
        }

        // backtrack: reassign columns along augmenting path
        while (j0 != 0) {
            const int k0 = j0 >> 6, l0 = j0 & 63;
            int wtmp; SEL15(way_reg, k0, wtmp);
            const int jprev = __shfl(wtmp, l0, 64);
            int pv;
            if (jprev == 0) {
                pv = i1v;
            } else {
                int ptmp; SEL15(p_reg, jprev >> 6, ptmp);
                pv = __shfl(ptmp, jprev & 63, 64);
            }
            if (t == l0) SET15(p_reg, k0, pv);
            if (t == pv - 1) rowcol = j0;    // row->column mirror
            j0 = jprev;
        }
    }

    outPred[b * Mv + t] = (float)(rowcol - 1);
    outTgt[b * Mv + t]  = (float)t;
}

// ---------------------------------------------------------------------------
extern "C" void kernel_launch(void* const* d_in, const int* in_sizes, int n_in,
                              void* d_out, int out_size, void* d_ws, size_t ws_size,
                              hipStream_t stream)
{
    (void)in_sizes; (void)n_in; (void)out_size;

    const float* logits  = (const float*)d_in[0];   // [64,900,128] f32
    const float* corners = (const float*)d_in[1];   // [64,900,8,3] f32
    const int*   labels  = (const int*)  d_in[2];   // [64,64] i32
    const float* boxes   = (const float*)d_in[3];   // [64,64,7] f32

    float* out  = (float*)d_out;
    float* Cc   = out;                               // [64,900,64]
    float* pred = out + (size_t)Bv * Nv * Mv;        // [64,64] as f32
    float* tgt  = pred + (size_t)Bv * Mv;            // [64,64] as f32

    cost_kernel<<<dim3(Nv, Bv), 64, 0, stream>>>(logits, corners, labels, boxes, Cc);

    const size_t ctBytes = (size_t)Bv * Mv * Nv * sizeof(float);
    float* CT = (ws_size >= ctBytes) ? (float*)d_ws : nullptr;
    lsa_kernel<<<Bv, 64, 0, stream>>>(Cc, CT, pred, tgt);
}